// Round 3
// baseline (219.000 us; speedup 1.0000x reference)
//
#include <hip/hip_runtime.h>
#include <hip/hip_bf16.h>
#include <stdint.h>

#define DI __device__ __forceinline__

typedef float f32x4 __attribute__((ext_vector_type(4)));
typedef short bf16x8 __attribute__((ext_vector_type(8)));

DI uint16_t f2bf(float f) {
    union { float f; uint32_t u; } v; v.f = f;
    uint32_t r = v.u + 0x7FFF + ((v.u >> 16) & 1);
    return (uint16_t)(r >> 16);
}
DI float bf2f(uint16_t h) {
    union { uint32_t u; float f; } v; v.u = ((uint32_t)h) << 16;
    return v.f;
}
DI uint32_t pk_bf16(float x, float y) {   // RNE pack via v_cvt_pk_bf16_f32
    __hip_bfloat162 h = __float22bfloat162_rn(make_float2(x, y));
    union { __hip_bfloat162 h; uint32_t u; } v; v.h = h; return v.u;
}
// async global->LDS, 16B per lane; LDS dest = wave-uniform base + lane*16
DI void gl_lds16(const void* g, void* l) {
    __builtin_amdgcn_global_load_lds(
        (__attribute__((address_space(1))) void*)(uintptr_t)g,
        (__attribute__((address_space(3))) void*)(uintptr_t)l,
        16, 0, 0);
}

// ---------------- kernel 0: Wc^T bf16 (pad 31->32) ------------------------
__global__ void k_init(const float* __restrict__ Wc, uint16_t* __restrict__ WcT) {
    int tid = threadIdx.x;
    for (int idx = tid; idx < 32 * 256; idx += 256) {
        int n = idx >> 8, k = idx & 255;
        WcT[idx] = (n < 31) ? f2bf(Wc[k * 31 + n]) : (uint16_t)0;
    }
}

// ---------------- kernel 1: Wb [2048][256] -> WbT bf16 [256][2048] --------
__global__ void k_transpose_wb(const float* __restrict__ Wb, uint16_t* __restrict__ WbT) {
    __shared__ float t[32][33];
    int kb = blockIdx.x, nb = blockIdx.y;
    int tx = threadIdx.x & 31, ty0 = (threadIdx.x >> 5) * 4;
    for (int i = 0; i < 4; ++i)
        t[ty0 + i][tx] = Wb[(kb * 32 + ty0 + i) * 256 + nb * 32 + tx];
    __syncthreads();
    for (int i = 0; i < 4; ++i)
        WbT[(nb * 32 + ty0 + i) * 2048 + kb * 32 + tx] = f2bf(t[tx][ty0 + i]);
}

// ---------------- kernel 2: Y = relu([src;tar] @ Wb + bb), bf16 out -------
// Barrier-free register-streaming GEMM. Block = 4 waves; wave = m16 x n64.
// A direct from HBM (prefetch distance 2), B direct from L2 (distance 1).
__launch_bounds__(256)
__global__ void k_bottleneck(const float* __restrict__ src, const float* __restrict__ tgt,
                             const uint16_t* __restrict__ WbT, const float* __restrict__ bbias,
                             uint16_t* __restrict__ Y) {
    int tid = threadIdx.x, lane = tid & 63, w = tid >> 6;
    int bm = blockIdx.x >> 2, bn = blockIdx.x & 3;  // n-siblings adjacent -> L3 reuse of A
    int rowbase = bm * 64 + w * 16;
    const float* Xr = (rowbase < 4096) ? src + (size_t)rowbase * 2048
                                       : tgt + (size_t)(rowbase - 4096) * 2048;
    int rl = lane & 15, kq = lane >> 4;
    const float* Ab = Xr + (size_t)rl * 2048 + kq * 8;
    int n0 = bn * 64;
    const uint16_t* Bb = WbT + (size_t)(n0 + rl) * 2048 + kq * 8;

    f32x4 acc[4] = {};
    float4 ar[4][4];     // [buf][kb*2 + half]
    bf16x8 br[2][2][4];  // [buf][kb][nf]

    auto loadA = [&](int buf, int t) {
        const float* p = Ab + t * 64;
        ar[buf][0] = *(const float4*)(p);
        ar[buf][1] = *(const float4*)(p + 4);
        ar[buf][2] = *(const float4*)(p + 32);
        ar[buf][3] = *(const float4*)(p + 36);
    };
    auto loadB = [&](int buf, int t) {
        const uint16_t* p = Bb + t * 64;
        for (int nf = 0; nf < 4; ++nf) {
            br[buf][0][nf] = *(const bf16x8*)(p + nf * 16 * 2048);
            br[buf][1][nf] = *(const bf16x8*)(p + nf * 16 * 2048 + 32);
        }
    };
    loadA(0, 0); loadA(1, 1); loadB(0, 0);

#pragma unroll 4
    for (int t = 0; t < 32; ++t) {
        int abuf = t & 3, bbuf = t & 1;
        if (t < 30) loadA((t + 2) & 3, t + 2);
        if (t < 31) loadB(bbuf ^ 1, t + 1);
        union { uint4 u; bf16x8 v; } a0, a1;
        a0.u.x = pk_bf16(ar[abuf][0].x, ar[abuf][0].y);
        a0.u.y = pk_bf16(ar[abuf][0].z, ar[abuf][0].w);
        a0.u.z = pk_bf16(ar[abuf][1].x, ar[abuf][1].y);
        a0.u.w = pk_bf16(ar[abuf][1].z, ar[abuf][1].w);
        a1.u.x = pk_bf16(ar[abuf][2].x, ar[abuf][2].y);
        a1.u.y = pk_bf16(ar[abuf][2].z, ar[abuf][2].w);
        a1.u.z = pk_bf16(ar[abuf][3].x, ar[abuf][3].y);
        a1.u.w = pk_bf16(ar[abuf][3].z, ar[abuf][3].w);
#pragma unroll
        for (int nf = 0; nf < 4; ++nf)
            acc[nf] = __builtin_amdgcn_mfma_f32_16x16x32_bf16(a0.v, br[bbuf][0][nf], acc[nf], 0, 0, 0);
#pragma unroll
        for (int nf = 0; nf < 4; ++nf)
            acc[nf] = __builtin_amdgcn_mfma_f32_16x16x32_bf16(a1.v, br[bbuf][1][nf], acc[nf], 0, 0, 0);
    }
    for (int nf = 0; nf < 4; ++nf) {
        int col = n0 + nf * 16 + rl;
        float bias = bbias[col];
        for (int j = 0; j < 4; ++j) {
            int row = rowbase + kq * 4 + j;
            float v = fmaxf(acc[nf][j] + bias, 0.f);
            Y[(size_t)row * 256 + col] = f2bf(v);
        }
    }
}

// ---------------- kernel 3: row sum-of-squares --------------------------
__global__ void k_rowstats(const uint16_t* __restrict__ Y, float* __restrict__ s2t2) {
    int row = blockIdx.x * 4 + (threadIdx.x >> 6);
    int lane = threadIdx.x & 63;
    ushort4 v = *(const ushort4*)(Y + (size_t)row * 256 + lane * 4);
    float a = bf2f(v.x), b = bf2f(v.y), c = bf2f(v.z), d = bf2f(v.w);
    float s = a * a + b * b + c * c + d * d;
    for (int m = 1; m < 64; m <<= 1) s += __shfl_xor(s, m);
    if (lane == 0) s2t2[row] = s;
}

// ---------------- kernel 4: column partial sums (coalesced) -------------
__global__ void k_colsum(const uint16_t* __restrict__ Y, float* __restrict__ part) {
    __shared__ float sred[4][256];
    int tid = threadIdx.x, cg = tid & 63, rs = tid >> 6;
    int r0 = blockIdx.x * 64;
    float a0 = 0.f, a1 = 0.f, a2 = 0.f, a3 = 0.f;
    for (int r = r0 + rs; r < r0 + 64; r += 4) {
        ushort4 v = *(const ushort4*)(Y + (size_t)r * 256 + cg * 4);
        a0 += bf2f(v.x); a1 += bf2f(v.y); a2 += bf2f(v.z); a3 += bf2f(v.w);
    }
    sred[rs][cg * 4 + 0] = a0; sred[rs][cg * 4 + 1] = a1;
    sred[rs][cg * 4 + 2] = a2; sred[rs][cg * 4 + 3] = a3;
    __syncthreads();
    if (rs == 0)
        for (int i = 0; i < 4; ++i) {
            int col = cg * 4 + i;
            part[blockIdx.x * 256 + col] =
                sred[0][col] + sred[1][col] + sred[2][col] + sred[3][col];
        }
}

// ---------------- kernel 5: classifier (wave-level, barrier-free) --------
__launch_bounds__(64)
__global__ void k_classifier(const uint16_t* __restrict__ Y, const uint16_t* __restrict__ WcT,
                             const float* __restrict__ bc, const int* __restrict__ labels,
                             float* __restrict__ out_margin, float* __restrict__ ce_part) {
    int lane = threadIdx.x;
    int r0 = blockIdx.x * 16;
    bool is_src = (r0 < 4096);
    int rl = lane & 15, kq = lane >> 4;
    const uint16_t* Ap = Y + (size_t)(r0 + rl) * 256 + kq * 8;
    const uint16_t* Bp = WcT + (size_t)rl * 256 + kq * 8;
    f32x4 acc[2] = {};
#pragma unroll
    for (int kb = 0; kb < 8; ++kb) {
        bf16x8 a  = *(const bf16x8*)(Ap + kb * 32);
        bf16x8 b0 = *(const bf16x8*)(Bp + kb * 32);
        bf16x8 b1 = *(const bf16x8*)(Bp + 16 * 256 + kb * 32);
        acc[0] = __builtin_amdgcn_mfma_f32_16x16x32_bf16(a, b0, acc[0], 0, 0, 0);
        acc[1] = __builtin_amdgcn_mfma_f32_16x16x32_bf16(a, b1, acc[1], 0, 0, 0);
    }
    int c0 = rl, c1 = 16 + rl;
    float bc0 = bc[c0];
    float bc1 = (c1 < 31) ? bc[c1] : 0.f;
    float ce_local = 0.f;
    for (int j = 0; j < 4; ++j) {
        int row = r0 + kq * 4 + j;
        float v0 = acc[0][j] + bc0;
        float v1 = (c1 < 31) ? (acc[1][j] + bc1) : -1e30f;
        float mx = fmaxf(v0, v1);
        for (int m = 1; m < 16; m <<= 1) mx = fmaxf(mx, __shfl_xor(mx, m, 16));
        float e0 = __expf(v0 - mx);
        float e1 = (c1 < 31) ? __expf(v1 - mx) : 0.f;
        float ssum = e0 + e1;
        for (int m = 1; m < 16; m <<= 1) ssum += __shfl_xor(ssum, m, 16);
        float inv = 1.f / ssum;
        float conf0 = e0 * inv, conf1 = e1 * inv;
        int lab;
        if (is_src) {
            lab = labels[row];
        } else {
            float bv; int bi;
            if (v0 >= v1) { bv = v0; bi = c0; } else { bv = v1; bi = c1; }
            for (int m = 1; m < 16; m <<= 1) {
                float ov = __shfl_xor(bv, m, 16);
                int oi = __shfl_xor(bi, m, 16);
                if (ov > bv || (ov == bv && oi < bi)) { bv = ov; bi = oi; }
            }
            lab = bi;
        }
        float tc = (c0 == lab ? conf0 : 0.f) + (c1 == lab ? conf1 : 0.f);
        for (int m = 1; m < 16; m <<= 1) tc += __shfl_xor(tc, m, 16);
        float ex = fmaxf(c0 == lab ? -1.f : conf0,
                         (c1 == lab || c1 >= 31) ? -1.f : conf1);
        for (int m = 1; m < 16; m <<= 1) ex = fmaxf(ex, __shfl_xor(ex, m, 16));
        if (c0 == 0) out_margin[row] = tc - ex;
        if (is_src) {
            float vl = (c0 == lab) ? v0 : ((c1 == lab) ? v1 : -1e30f);
            for (int m = 1; m < 16; m <<= 1) vl = fmaxf(vl, __shfl_xor(vl, m, 16));
            if (c0 == 0) ce_local += -(vl - mx - __logf(ssum));
        }
    }
    ce_local += __shfl_xor(ce_local, 16);
    ce_local += __shfl_xor(ce_local, 32);
    if (lane == 0) ce_part[blockIdx.x] = is_src ? ce_local : 0.f;
}

// ---------------- kernel 6: pairwise d2 -> exp partial sums -------------
// 128x128 tile, K=256 in 4 phases of 64 -> 32KB LDS -> 3 blocks/CU
__launch_bounds__(256)
__global__ void k_pairwise(const uint16_t* __restrict__ Y, const float* __restrict__ s2t2,
                           float* __restrict__ gk_part) {
    __shared__ __align__(16) uint8_t lds[32768];  // A 16KB @0, B 16KB @16384
    int tid = threadIdx.x, lane = tid & 63, w = tid >> 6;
    int m0 = blockIdx.x * 128, n0 = blockIdx.y * 128;
    int cc = (lane >> 4) ^ (lane & 3) ^ ((lane >> 2) & 3);
    int wm = (w & 1) * 64, wn = (w >> 1) * 64;
    f32x4 acc[4][4] = {};
    for (int h = 0; h < 4; ++h) {
        if (h) __syncthreads();
        int k0 = h * 64;
        for (int i = 0; i < 4; ++i) {
            int s = w * 4 + i;
            int kb = s >> 3, r0 = (s & 7) * 16;
            int r = r0 + (lane >> 2), p = lane & 3;
            int c = p ^ (r & 3) ^ ((r >> 2) & 3);
            gl_lds16(Y + (size_t)(m0 + r) * 256 + k0 + kb * 32 + c * 8, lds + s * 1024);
            gl_lds16(Y + (size_t)(4096 + n0 + r) * 256 + k0 + kb * 32 + c * 8,
                     lds + 16384 + s * 1024);
        }
        __syncthreads();
        for (int kb = 0; kb < 2; ++kb) {
            bf16x8 a[4], b[4];
            for (int mi = 0; mi < 4; ++mi) {
                int r = wm + mi * 16 + (lane & 15);
                a[mi] = *(const bf16x8*)(lds + kb * 8192 + r * 64 + cc * 16);
            }
            for (int nf = 0; nf < 4; ++nf) {
                int rn = wn + nf * 16 + (lane & 15);
                b[nf] = *(const bf16x8*)(lds + 16384 + kb * 8192 + rn * 64 + cc * 16);
            }
            for (int mi = 0; mi < 4; ++mi)
                for (int nf = 0; nf < 4; ++nf)
                    acc[mi][nf] = __builtin_amdgcn_mfma_f32_16x16x32_bf16(
                        a[mi], b[nf], acc[mi][nf], 0, 0, 0);
        }
    }
    float t2v[4];
    for (int nf = 0; nf < 4; ++nf)
        t2v[nf] = s2t2[4096 + n0 + wn + nf * 16 + (lane & 15)];
    float g1 = 0.f, g5 = 0.f;
    for (int mi = 0; mi < 4; ++mi) {
        int rbase = m0 + wm + mi * 16 + (lane >> 4) * 4;
        float s2v[4];
        for (int j = 0; j < 4; ++j) s2v[j] = s2t2[rbase + j];
        for (int nf = 0; nf < 4; ++nf)
            for (int j = 0; j < 4; ++j) {
                float d2 = s2v[j] + t2v[nf] - 2.f * acc[mi][nf][j];
                d2 = fmaxf(d2, 0.f);
                g1 += __expf(-0.5f * d2);
                g5 += __expf(-0.02f * d2);
            }
    }
    for (int m = 1; m < 64; m <<= 1) { g1 += __shfl_xor(g1, m); g5 += __shfl_xor(g5, m); }
    __syncthreads();
    float* red = (float*)lds;
    if (lane == 0) { red[w * 2] = g1; red[w * 2 + 1] = g5; }
    __syncthreads();
    if (tid == 0) {
        int bid = blockIdx.y * 32 + blockIdx.x;
        gk_part[bid * 2]     = red[0] + red[2] + red[4] + red[6];
        gk_part[bid * 2 + 1] = red[1] + red[3] + red[5] + red[7];
    }
}

// ---------------- kernel 7: finalize scalars ----------------------------
__global__ void k_finalize(const float* __restrict__ colsum_part,
                           const float* __restrict__ gk_part,
                           const float* __restrict__ ce_part, float* __restrict__ d_out) {
    __shared__ float red[4][4];
    int tid = threadIdx.x, lane = tid & 63, w = tid >> 6;
    float cs = 0.f, ct = 0.f;
    for (int b = 0; b < 64; ++b)   cs += colsum_part[b * 256 + tid];
    for (int b = 64; b < 128; ++b) ct += colsum_part[b * 256 + tid];
    float delta = (cs - ct) * (1.f / 4096.f);
    float sq = delta * delta;
    float g1 = 0.f, g5 = 0.f;
    for (int i = 0; i < 4; ++i) {
        int p = tid * 4 + i;
        g1 += gk_part[p * 2];
        g5 += gk_part[p * 2 + 1];
    }
    float ce = ce_part[tid] + ce_part[tid + 256];
    for (int m = 1; m < 64; m <<= 1) {
        sq += __shfl_xor(sq, m);
        g1 += __shfl_xor(g1, m);
        g5 += __shfl_xor(g5, m);
        ce += __shfl_xor(ce, m);
    }
    if (lane == 0) { red[w][0] = sq; red[w][1] = g1; red[w][2] = g5; red[w][3] = ce; }
    __syncthreads();
    if (tid == 0) {
        d_out[0] = (red[0][3] + red[1][3] + red[2][3] + red[3][3]) * (1.f / 4096.f);
        d_out[1] = red[0][0] + red[1][0] + red[2][0] + red[3][0];
        d_out[2] = (red[0][1] + red[1][1] + red[2][1] + red[3][1]) * 5.9604644775390625e-08f;
        d_out[3] = (red[0][2] + red[1][2] + red[2][2] + red[3][2]) * 5.9604644775390625e-08f;
    }
}

extern "C" void kernel_launch(void* const* d_in, const int* in_sizes, int n_in,
                              void* d_out, int out_size, void* d_ws, size_t ws_size,
                              hipStream_t stream) {
    const float* source = (const float*)d_in[0];
    const float* target = (const float*)d_in[1];
    const float* Wb     = (const float*)d_in[2];
    const float* bb     = (const float*)d_in[3];
    const float* Wc     = (const float*)d_in[4];
    const float* bc     = (const float*)d_in[5];
    const int*   labels = (const int*)d_in[6];
    float* out = (float*)d_out;
    uint8_t* ws = (uint8_t*)d_ws;

    uint16_t* Y    = (uint16_t*)(ws);                 // 4 MB
    uint16_t* WbT  = (uint16_t*)(ws + 4194304);       // 1 MB (dead after k_bottleneck)
    uint16_t* WcT  = (uint16_t*)(ws + 5242880);       // 16 KB
    float*    s2t2 = (float*)(ws + 5259264);          // 32 KB
    // alias dead WbT region (WbT only read by k_bottleneck, which runs first):
    float* colsum_part = (float*)(ws + 4194304);            // 128*256*4 = 128 KB
    float* gk_part     = (float*)(ws + 4194304 + 131072);   // 1024*2*4 = 8 KB
    float* ce_part     = (float*)(ws + 4194304 + 139264);   // 512*4 = 2 KB

    k_init<<<1, 256, 0, stream>>>(Wc, WcT);
    k_transpose_wb<<<dim3(64, 8), 256, 0, stream>>>(Wb, WbT);
    k_bottleneck<<<512, 256, 0, stream>>>(source, target, WbT, bb, Y);
    k_rowstats<<<2048, 256, 0, stream>>>(Y, s2t2);
    k_colsum<<<128, 256, 0, stream>>>(Y, colsum_part);
    k_classifier<<<512, 64, 0, stream>>>(Y, WcT, bc, labels, out + 4, ce_part);
    k_pairwise<<<dim3(32, 32), 256, 0, stream>>>(Y, s2t2, gk_part);
    k_finalize<<<1, 256, 0, stream>>>(colsum_part, gk_part, ce_part, out);
}

// Round 4
// 203.307 us; speedup vs baseline: 1.0772x; 1.0772x over previous
//
#include <hip/hip_runtime.h>
#include <hip/hip_bf16.h>
#include <stdint.h>

#define DI __device__ __forceinline__

typedef float f32x4 __attribute__((ext_vector_type(4)));
typedef short bf16x8 __attribute__((ext_vector_type(8)));

DI uint16_t f2bf(float f) {
    union { float f; uint32_t u; } v; v.f = f;
    uint32_t r = v.u + 0x7FFF + ((v.u >> 16) & 1);
    return (uint16_t)(r >> 16);
}
DI float bf2f(uint16_t h) {
    union { uint32_t u; float f; } v; v.u = ((uint32_t)h) << 16;
    return v.f;
}
DI uint32_t pk_bf16(float x, float y) {   // RNE pack via v_cvt_pk_bf16_f32
    __hip_bfloat162 h = __float22bfloat162_rn(make_float2(x, y));
    union { __hip_bfloat162 h; uint32_t u; } v; v.h = h; return v.u;
}
// async global->LDS, 16B per lane; LDS dest = wave-uniform base + lane*16
DI void gl_lds16(const void* g, void* l) {
    __builtin_amdgcn_global_load_lds(
        (__attribute__((address_space(1))) void*)(uintptr_t)g,
        (__attribute__((address_space(3))) void*)(uintptr_t)l,
        16, 0, 0);
}

// ---------------- kernel 0: Wb transpose + WcT init (fused) ---------------
// blocks 0..511: Wb [2048][256] -> WbT bf16 [256][2048]; block 512: WcT
__global__ void k_prep(const float* __restrict__ Wb, uint16_t* __restrict__ WbT,
                       const float* __restrict__ Wc, uint16_t* __restrict__ WcT) {
    if (blockIdx.x == 512) {
        int tid = threadIdx.x;
        for (int idx = tid; idx < 32 * 256; idx += 256) {
            int n = idx >> 8, k = idx & 255;
            WcT[idx] = (n < 31) ? f2bf(Wc[k * 31 + n]) : (uint16_t)0;
        }
        return;
    }
    __shared__ float t[32][33];
    int kb = blockIdx.x & 63, nb = blockIdx.x >> 6;
    int tx = threadIdx.x & 31, ty0 = (threadIdx.x >> 5) * 4;
    for (int i = 0; i < 4; ++i)
        t[ty0 + i][tx] = Wb[(kb * 32 + ty0 + i) * 256 + nb * 32 + tx];
    __syncthreads();
    for (int i = 0; i < 4; ++i)
        WbT[(nb * 32 + ty0 + i) * 2048 + kb * 32 + tx] = f2bf(t[tx][ty0 + i]);
}

// ---------------- kernel 1: Y = relu([src;tar] @ Wb + bb), bf16 out -------
// m32 x n64 tile, BK=128, grid 1024 (4 blocks/CU), fragment-major LDS
// (every ds_read_b128 is base + lane*16: zero bank conflicts).
__launch_bounds__(256, 4)
__global__ void k_bottleneck(const float* __restrict__ src, const float* __restrict__ tgt,
                             const uint16_t* __restrict__ WbT, const float* __restrict__ bbias,
                             uint16_t* __restrict__ Y) {
    __shared__ __align__(16) uint8_t lds[24576];   // A 8KB @0, B 16KB @8192
    int tid = threadIdx.x, lane = tid & 63, w = tid >> 6;
    int bm = blockIdx.x >> 2, bn = blockIdx.x & 3;  // n-siblings adjacent
    int rowbase = bm * 32, n0 = bn * 64;
    const float* Xr = (rowbase < 4096) ? src + (size_t)rowbase * 2048
                                       : tgt + (size_t)(rowbase - 4096) * 2048;
    int rl = lane & 15, kq = lane >> 4;

    // A staging: thread handles segs s=(tid>>6) and s+4.
    // seg s: kb=s>>1, mi=s&1 -> A[mi*16+rl][kb*32 + kq*8 ..]
    int as = tid >> 6;
    const float* Ag = Xr + (size_t)((as & 1) * 16 + rl) * 2048 + (as >> 1) * 32 + kq * 8;
    uint8_t* Aw0 = lds + tid * 16;          // seg s
    uint8_t* Aw1 = lds + 4096 + tid * 16;   // seg s+4 (kb+2)

    // B staging: wave w handles segs sb = w*4 + i (i 0..3): kb=sb>>2, wseg=sb&3
    const uint16_t* Bg[4];
    uint8_t* Bl[4];
    for (int i = 0; i < 4; ++i) {
        int sb = w * 4 + i, kb = sb >> 2, wseg = sb & 3;
        Bg[i] = WbT + (size_t)(n0 + wseg * 16 + rl) * 2048 + kb * 32 + kq * 8;
        Bl[i] = lds + 8192 + sb * 1024;
    }

    f32x4 acc[2] = {};
    for (int t = 0; t < 16; ++t) {
        if (t) __syncthreads();
        int k0 = t * 128;
        for (int i = 0; i < 4; ++i) gl_lds16(Bg[i] + k0, Bl[i]);
        float4 x0 = *(const float4*)(Ag + k0);
        float4 x1 = *(const float4*)(Ag + k0 + 4);
        float4 x2 = *(const float4*)(Ag + k0 + 64);
        float4 x3 = *(const float4*)(Ag + k0 + 68);
        uint4 u0, u1;
        u0.x = pk_bf16(x0.x, x0.y); u0.y = pk_bf16(x0.z, x0.w);
        u0.z = pk_bf16(x1.x, x1.y); u0.w = pk_bf16(x1.z, x1.w);
        u1.x = pk_bf16(x2.x, x2.y); u1.y = pk_bf16(x2.z, x2.w);
        u1.z = pk_bf16(x3.x, x3.y); u1.w = pk_bf16(x3.z, x3.w);
        *(uint4*)Aw0 = u0;
        *(uint4*)Aw1 = u1;
        __syncthreads();
#pragma unroll
        for (int kb = 0; kb < 4; ++kb) {
            bf16x8 a0 = *(const bf16x8*)(lds + kb * 2048 + lane * 16);
            bf16x8 a1 = *(const bf16x8*)(lds + kb * 2048 + 1024 + lane * 16);
            bf16x8 b  = *(const bf16x8*)(lds + 8192 + kb * 4096 + w * 1024 + lane * 16);
            acc[0] = __builtin_amdgcn_mfma_f32_16x16x32_bf16(a0, b, acc[0], 0, 0, 0);
            acc[1] = __builtin_amdgcn_mfma_f32_16x16x32_bf16(a1, b, acc[1], 0, 0, 0);
        }
    }
    int col = n0 + w * 16 + rl;
    float bias = bbias[col];
    for (int mi = 0; mi < 2; ++mi)
        for (int j = 0; j < 4; ++j) {
            int row = rowbase + mi * 16 + kq * 4 + j;
            float v = fmaxf(acc[mi][j] + bias, 0.f);
            Y[(size_t)row * 256 + col] = f2bf(v);
        }
}

// ---------------- kernel 2: fused row sum-of-squares + column partials ---
// grid 512, block 256; block covers 16 rows.
__global__ void k_stats(const uint16_t* __restrict__ Y, float* __restrict__ s2t2,
                        float* __restrict__ part) {
    __shared__ float sred[4][256];
    int tid = threadIdx.x, cg = tid & 63, rs = tid >> 6;
    int r0 = blockIdx.x * 16;
    float a0 = 0.f, a1 = 0.f, a2 = 0.f, a3 = 0.f;
    for (int it = 0; it < 4; ++it) {
        int row = r0 + it * 4 + rs;
        ushort4 v = *(const ushort4*)(Y + (size_t)row * 256 + cg * 4);
        float f0 = bf2f(v.x), f1 = bf2f(v.y), f2 = bf2f(v.z), f3 = bf2f(v.w);
        a0 += f0; a1 += f1; a2 += f2; a3 += f3;
        float s = f0 * f0 + f1 * f1 + f2 * f2 + f3 * f3;
        for (int m = 1; m < 64; m <<= 1) s += __shfl_xor(s, m);
        if (cg == 0) s2t2[row] = s;
    }
    sred[rs][cg * 4 + 0] = a0; sred[rs][cg * 4 + 1] = a1;
    sred[rs][cg * 4 + 2] = a2; sred[rs][cg * 4 + 3] = a3;
    __syncthreads();
    if (rs == 0)
        for (int i = 0; i < 4; ++i) {
            int col = cg * 4 + i;
            part[blockIdx.x * 256 + col] =
                sred[0][col] + sred[1][col] + sred[2][col] + sred[3][col];
        }
}

// ---------------- kernel 3: classifier (wave-level, barrier-free) --------
__launch_bounds__(64)
__global__ void k_classifier(const uint16_t* __restrict__ Y, const uint16_t* __restrict__ WcT,
                             const float* __restrict__ bc, const int* __restrict__ labels,
                             float* __restrict__ out_margin, float* __restrict__ ce_part) {
    int lane = threadIdx.x;
    int r0 = blockIdx.x * 16;
    bool is_src = (r0 < 4096);
    int rl = lane & 15, kq = lane >> 4;
    const uint16_t* Ap = Y + (size_t)(r0 + rl) * 256 + kq * 8;
    const uint16_t* Bp = WcT + (size_t)rl * 256 + kq * 8;
    f32x4 acc[2] = {};
#pragma unroll
    for (int kb = 0; kb < 8; ++kb) {
        bf16x8 a  = *(const bf16x8*)(Ap + kb * 32);
        bf16x8 b0 = *(const bf16x8*)(Bp + kb * 32);
        bf16x8 b1 = *(const bf16x8*)(Bp + 16 * 256 + kb * 32);
        acc[0] = __builtin_amdgcn_mfma_f32_16x16x32_bf16(a, b0, acc[0], 0, 0, 0);
        acc[1] = __builtin_amdgcn_mfma_f32_16x16x32_bf16(a, b1, acc[1], 0, 0, 0);
    }
    int c0 = rl, c1 = 16 + rl;
    float bc0 = bc[c0];
    float bc1 = (c1 < 31) ? bc[c1] : 0.f;
    float ce_local = 0.f;
    for (int j = 0; j < 4; ++j) {
        int row = r0 + kq * 4 + j;
        float v0 = acc[0][j] + bc0;
        float v1 = (c1 < 31) ? (acc[1][j] + bc1) : -1e30f;
        float mx = fmaxf(v0, v1);
        for (int m = 1; m < 16; m <<= 1) mx = fmaxf(mx, __shfl_xor(mx, m, 16));
        float e0 = __expf(v0 - mx);
        float e1 = (c1 < 31) ? __expf(v1 - mx) : 0.f;
        float ssum = e0 + e1;
        for (int m = 1; m < 16; m <<= 1) ssum += __shfl_xor(ssum, m, 16);
        float inv = 1.f / ssum;
        float conf0 = e0 * inv, conf1 = e1 * inv;
        int lab;
        if (is_src) {
            lab = labels[row];
        } else {
            float bv; int bi;
            if (v0 >= v1) { bv = v0; bi = c0; } else { bv = v1; bi = c1; }
            for (int m = 1; m < 16; m <<= 1) {
                float ov = __shfl_xor(bv, m, 16);
                int oi = __shfl_xor(bi, m, 16);
                if (ov > bv || (ov == bv && oi < bi)) { bv = ov; bi = oi; }
            }
            lab = bi;
        }
        float tc = (c0 == lab ? conf0 : 0.f) + (c1 == lab ? conf1 : 0.f);
        for (int m = 1; m < 16; m <<= 1) tc += __shfl_xor(tc, m, 16);
        float ex = fmaxf(c0 == lab ? -1.f : conf0,
                         (c1 == lab || c1 >= 31) ? -1.f : conf1);
        for (int m = 1; m < 16; m <<= 1) ex = fmaxf(ex, __shfl_xor(ex, m, 16));
        if (c0 == 0) out_margin[row] = tc - ex;
        if (is_src) {
            float vl = (c0 == lab) ? v0 : ((c1 == lab) ? v1 : -1e30f);
            for (int m = 1; m < 16; m <<= 1) vl = fmaxf(vl, __shfl_xor(vl, m, 16));
            if (c0 == 0) ce_local += -(vl - mx - __logf(ssum));
        }
    }
    ce_local += __shfl_xor(ce_local, 16);
    ce_local += __shfl_xor(ce_local, 32);
    if (lane == 0) ce_part[blockIdx.x] = is_src ? ce_local : 0.f;
}

// ---------------- kernel 4: pairwise d2 -> exp partial sums -------------
// 128x128 tile, K=256 in 4 phases of 64 -> 32KB LDS -> 5 blocks/CU cap
__launch_bounds__(256)
__global__ void k_pairwise(const uint16_t* __restrict__ Y, const float* __restrict__ s2t2,
                           float* __restrict__ gk_part) {
    __shared__ __align__(16) uint8_t lds[32768];  // A 16KB @0, B 16KB @16384
    int tid = threadIdx.x, lane = tid & 63, w = tid >> 6;
    int m0 = blockIdx.x * 128, n0 = blockIdx.y * 128;
    int cc = (lane >> 4) ^ (lane & 3) ^ ((lane >> 2) & 3);
    int wm = (w & 1) * 64, wn = (w >> 1) * 64;
    f32x4 acc[4][4] = {};
    for (int h = 0; h < 4; ++h) {
        if (h) __syncthreads();
        int k0 = h * 64;
        for (int i = 0; i < 4; ++i) {
            int s = w * 4 + i;
            int kb = s >> 3, r0 = (s & 7) * 16;
            int r = r0 + (lane >> 2), p = lane & 3;
            int c = p ^ (r & 3) ^ ((r >> 2) & 3);
            gl_lds16(Y + (size_t)(m0 + r) * 256 + k0 + kb * 32 + c * 8, lds + s * 1024);
            gl_lds16(Y + (size_t)(4096 + n0 + r) * 256 + k0 + kb * 32 + c * 8,
                     lds + 16384 + s * 1024);
        }
        __syncthreads();
        for (int kb = 0; kb < 2; ++kb) {
            bf16x8 a[4], b[4];
            for (int mi = 0; mi < 4; ++mi) {
                int r = wm + mi * 16 + (lane & 15);
                a[mi] = *(const bf16x8*)(lds + kb * 8192 + r * 64 + cc * 16);
            }
            for (int nf = 0; nf < 4; ++nf) {
                int rn = wn + nf * 16 + (lane & 15);
                b[nf] = *(const bf16x8*)(lds + 16384 + kb * 8192 + rn * 64 + cc * 16);
            }
            for (int mi = 0; mi < 4; ++mi)
                for (int nf = 0; nf < 4; ++nf)
                    acc[mi][nf] = __builtin_amdgcn_mfma_f32_16x16x32_bf16(
                        a[mi], b[nf], acc[mi][nf], 0, 0, 0);
        }
    }
    float t2v[4];
    for (int nf = 0; nf < 4; ++nf)
        t2v[nf] = s2t2[4096 + n0 + wn + nf * 16 + (lane & 15)];
    float g1 = 0.f, g5 = 0.f;
    for (int mi = 0; mi < 4; ++mi) {
        int rbase = m0 + wm + mi * 16 + (lane >> 4) * 4;
        float s2v[4];
        for (int j = 0; j < 4; ++j) s2v[j] = s2t2[rbase + j];
        for (int nf = 0; nf < 4; ++nf)
            for (int j = 0; j < 4; ++j) {
                float d2 = s2v[j] + t2v[nf] - 2.f * acc[mi][nf][j];
                d2 = fmaxf(d2, 0.f);
                g1 += __expf(-0.5f * d2);
                g5 += __expf(-0.02f * d2);
            }
    }
    for (int m = 1; m < 64; m <<= 1) { g1 += __shfl_xor(g1, m); g5 += __shfl_xor(g5, m); }
    __syncthreads();
    float* red = (float*)lds;
    if (lane == 0) { red[w * 2] = g1; red[w * 2 + 1] = g5; }
    __syncthreads();
    if (tid == 0) {
        int bid = blockIdx.y * 32 + blockIdx.x;
        gk_part[bid * 2]     = red[0] + red[2] + red[4] + red[6];
        gk_part[bid * 2 + 1] = red[1] + red[3] + red[5] + red[7];
    }
}

// ---------------- kernel 5: finalize scalars ----------------------------
__global__ void k_finalize(const float* __restrict__ colsum_part,
                           const float* __restrict__ gk_part,
                           const float* __restrict__ ce_part, float* __restrict__ d_out) {
    __shared__ float red[4][4];
    int tid = threadIdx.x, lane = tid & 63, w = tid >> 6;
    float cs = 0.f, ct = 0.f;
    for (int b = 0; b < 256; ++b)   cs += colsum_part[b * 256 + tid];
    for (int b = 256; b < 512; ++b) ct += colsum_part[b * 256 + tid];
    float delta = (cs - ct) * (1.f / 4096.f);
    float sq = delta * delta;
    float g1 = 0.f, g5 = 0.f;
    for (int i = 0; i < 4; ++i) {
        int p = tid * 4 + i;
        g1 += gk_part[p * 2];
        g5 += gk_part[p * 2 + 1];
    }
    float ce = ce_part[tid] + ce_part[tid + 256];
    for (int m = 1; m < 64; m <<= 1) {
        sq += __shfl_xor(sq, m);
        g1 += __shfl_xor(g1, m);
        g5 += __shfl_xor(g5, m);
        ce += __shfl_xor(ce, m);
    }
    if (lane == 0) { red[w][0] = sq; red[w][1] = g1; red[w][2] = g5; red[w][3] = ce; }
    __syncthreads();
    if (tid == 0) {
        d_out[0] = (red[0][3] + red[1][3] + red[2][3] + red[3][3]) * (1.f / 4096.f);
        d_out[1] = red[0][0] + red[1][0] + red[2][0] + red[3][0];
        d_out[2] = (red[0][1] + red[1][1] + red[2][1] + red[3][1]) * 5.9604644775390625e-08f;
        d_out[3] = (red[0][2] + red[1][2] + red[2][2] + red[3][2]) * 5.9604644775390625e-08f;
    }
}

extern "C" void kernel_launch(void* const* d_in, const int* in_sizes, int n_in,
                              void* d_out, int out_size, void* d_ws, size_t ws_size,
                              hipStream_t stream) {
    const float* source = (const float*)d_in[0];
    const float* target = (const float*)d_in[1];
    const float* Wb     = (const float*)d_in[2];
    const float* bb     = (const float*)d_in[3];
    const float* Wc     = (const float*)d_in[4];
    const float* bc     = (const float*)d_in[5];
    const int*   labels = (const int*)d_in[6];
    float* out = (float*)d_out;
    uint8_t* ws = (uint8_t*)d_ws;

    uint16_t* Y    = (uint16_t*)(ws);                 // 4 MB
    uint16_t* WbT  = (uint16_t*)(ws + 4194304);       // 1 MB (dead after k_bottleneck)
    uint16_t* WcT  = (uint16_t*)(ws + 5242880);       // 16 KB
    float*    s2t2 = (float*)(ws + 5259264);          // 32 KB
    // alias dead WbT region (WbT only read by k_bottleneck, which runs first):
    float* colsum_part = (float*)(ws + 4194304);            // 512*256*4 = 512 KB
    float* gk_part     = (float*)(ws + 4194304 + 524288);   // 1024*2*4 = 8 KB
    float* ce_part     = (float*)(ws + 4194304 + 532480);   // 512*4 = 2 KB

    k_prep<<<513, 256, 0, stream>>>(Wb, WbT, Wc, WcT);
    k_bottleneck<<<1024, 256, 0, stream>>>(source, target, WbT, bb, Y);
    k_stats<<<512, 256, 0, stream>>>(Y, s2t2, colsum_part);
    k_classifier<<<512, 64, 0, stream>>>(Y, WcT, bc, labels, out + 4, ce_part);
    k_pairwise<<<dim3(32, 32), 256, 0, stream>>>(Y, s2t2, gk_part);
    k_finalize<<<1, 256, 0, stream>>>(colsum_part, gk_part, ce_part, out);
}